// Round 10
// baseline (14.591 us; speedup 1.0000x reference)
//
#include <hip/hip_runtime.h>

#define NF      2
#define NLOC    3072
#define NALL    4096
#define NNEI    128
#define NTYPES  4
#define NSPLINE 1024

// Opaque VGPR barrier: value becomes unknowable to the optimizer, so no
// contraction (mul+add->fma), reassociation, or approximation can cross it.
__device__ __forceinline__ float opaque(float x) {
    asm volatile("" : "+v"(x));
    return x;
}

// Prep: pack per-atom [x, y, z, bitcast(atype)] into float4 (raw bit moves).
__global__ __launch_bounds__(256) void pack_kernel(
    const float* __restrict__ coord,   // NF*NALL*3
    const int*   __restrict__ atype,   // NF*NALL
    float4*      __restrict__ packed)  // NF*NALL
{
    const int a = blockIdx.x * 256 + threadIdx.x;
    if (a < NF * NALL) {
        const float* c = coord + (size_t)a * 3;
        float4 p;
        p.x = c[0]; p.y = c[1]; p.z = c[2];
        p.w = __int_as_float(atype[a]);
        packed[a] = p;
    }
}

// One thread per (row, neighbor). 256-thread block = 2 rows x 128 neighbors.
__global__ __launch_bounds__(256) void pairtab_kernel(
    const float4* __restrict__ packed,   // NF*NALL  [x,y,z,type]
    const int*    __restrict__ nlist,    // NF*NLOC*NNEI
    const float*  __restrict__ tab_info, // 3
    const float*  __restrict__ tab_data, // NTYPES*NTYPES*NSPLINE*4
    float*        __restrict__ out)      // NF*NLOC
{
    const int tid = threadIdx.x;
    const int r   = tid >> 7;            // row within block (0..1)
    const int jj  = tid & 127;           // neighbor index
    const int row = blockIdx.x * 2 + r;

    const int f = (row >= NLOC) ? 1 : 0;
    const int i = row - f * NLOC;

    const float rmin = tab_info[0];
    const float hh   = tab_info[1];
    // DeePMD numpy: hi = 1.0/hh (CR f32 via f64-div+round, double-rounding safe)
    const float hi   = opaque((float)(1.0 / (double)hh));
    const float cut2 = opaque(opaque(1024.0f * hh) + rmin);

    // self atom: one broadcast dwordx4 (all 128 row-threads same address)
    const float4 pi = packed[f * NALL + i];
    const float xi = pi.x, yi = pi.y, zi = pi.z;
    const int itype = __float_as_int(pi.w);

    const int nj = nlist[(size_t)(f * NLOC + i) * NNEI + jj];
    const int mj = (nj < 0) ? 0 : nj;

    // neighbor atom: ONE dwordx4 gather gets coord + type
    const float4 pj = packed[f * NALL + mj];
    const int jtype = __float_as_int(pj.w);

    // ---- strict f32, numpy association, every op barriered (no FMA) ----
    const float dx = opaque(xi - pj.x);
    const float dy = opaque(yi - pj.y);
    const float dz = opaque(zi - pj.z);
    const float x2 = opaque(dx * dx);
    const float y2 = opaque(dy * dy);
    const float z2 = opaque(dz * dz);
    float ss = opaque(opaque(x2 + y2) + z2);
    ss = fmaxf(ss, 1e-30f);

    // CR f32 sqrt, flag-immune: f64 sqrt then round (double-rounding safe)
    const float rr = (float)sqrt((double)ss);

    // uu = (rr - rmin) * hi  (f32 sub, f32 mul — DeePMD numpy recip-multiply)
    const float num = opaque(rr - rmin);
    float uu = opaque(num * hi);
    if (nj == -1) uu = (float)(NSPLINE + 1);

    const int idx = (int)uu;                  // trunc, uu >= 0
    const float fu = opaque(uu - (float)idx);
    int cidx = idx;
    if (cidx < 0) cidx = 0;
    if (cidx > NSPLINE - 1) cidx = NSPLINE - 1;

    const float4 c4 = *(const float4*)(tab_data +
        ((size_t)((itype * NTYPES + jtype) * NSPLINE + cidx)) * 4);

    float a3 = c4.x, a2 = c4.y, a1 = c4.z, a0 = c4.w;
    if (idx > NSPLINE) { a3 = 0.f; a2 = 0.f; a1 = 0.f; a0 = 0.f; }

    // f32 unfused Horner (DeePMD _calculate_ener)
    float e = opaque(opaque(opaque(opaque(opaque(a3 * fu) + a2) * fu)
                            + a1) * fu) + a0;

    if (rr >= 6.0f || rr >= cut2 || nj == -1) e = 0.0f;

    // ---- reduction: wave shfl + LDS combine (2 waves per row) ----
    double acc = (double)e;
    #pragma unroll
    for (int off = 32; off; off >>= 1)
        acc += __shfl_xor(acc, off);

    __shared__ double part[4];
    if ((tid & 63) == 0) part[tid >> 6] = acc;
    __syncthreads();
    if (jj == 0)
        out[row] = (float)(0.5 * (part[r * 2] + part[r * 2 + 1]));
}

extern "C" void kernel_launch(void* const* d_in, const int* in_sizes, int n_in,
                              void* d_out, int out_size, void* d_ws, size_t ws_size,
                              hipStream_t stream) {
    const float* coord    = (const float*)d_in[0];
    const int*   atype    = (const int*)  d_in[1];
    const int*   nlist    = (const int*)  d_in[2];
    const float* tab_info = (const float*)d_in[3];
    const float* tab_data = (const float*)d_in[4];
    float* out = (float*)d_out;
    float4* packed = (float4*)d_ws;              // 8192 * 16 B = 128 KB

    const int atoms = NF * NALL;                 // 8192
    pack_kernel<<<(atoms + 255) / 256, 256, 0, stream>>>(coord, atype, packed);

    const int blocks = (NF * NLOC) / 2;          // 3072 blocks, 2 rows each
    pairtab_kernel<<<blocks, 256, 0, stream>>>(packed, nlist, tab_info,
                                               tab_data, out);
}

// Round 12
// 13.000 us; speedup vs baseline: 1.1224x; 1.1224x over previous
//
#include <hip/hip_runtime.h>

#define NF      2
#define NLOC    3072
#define NALL    4096
#define NNEI    128
#define NTYPES  4
#define NSPLINE 1024
#define RPB     8            // rows per block (3072 % 8 == 0 -> same frame)

typedef float f32x4 __attribute__((ext_vector_type(4)));

// Opaque VGPR barrier: value becomes unknowable to the optimizer, so no
// contraction (mul+add->fma), reassociation, or approximation can cross it.
__device__ __forceinline__ float opaque(float x) {
    asm volatile("" : "+v"(x));
    return x;
}

__global__ __launch_bounds__(1024) void pairtab_kernel(
    const float* __restrict__ coord,     // NF*NALL*3
    const int*   __restrict__ atype,     // NF*NALL
    const int*   __restrict__ nlist,     // NF*NLOC*NNEI
    const float* __restrict__ tab_info,  // 3
    const float* __restrict__ tab_data,  // NTYPES*NTYPES*NSPLINE*4
    float*       __restrict__ out)       // NF*NLOC
{
    __shared__ f32x4  atoms[NALL];       // 64 KB: [x,y,z,bitcast(type)] per atom
    __shared__ double part[16];
    float* ldsf = (float*)atoms;

    const int tid  = threadIdx.x;
    const int row0 = blockIdx.x * RPB;
    const int f    = (row0 >= NLOC) ? 1 : 0;

    // ---- stage this frame's atoms into LDS (coalesced) ----
    const float* cbase = coord + (size_t)f * NALL * 3;
    #pragma unroll
    for (int g = tid; g < NALL * 3; g += 1024) {
        const float v = cbase[g];
        const int a = g / 3;             // compiler magic-mul
        const int comp = g - a * 3;
        ldsf[a * 4 + comp] = v;
    }
    const int* tb = atype + (size_t)f * NALL;
    #pragma unroll
    for (int g = tid; g < NALL; g += 1024)
        ldsf[g * 4 + 3] = __int_as_float(tb[g]);
    __syncthreads();

    // ---- one interaction per thread: 8 rows x 128 neighbors ----
    const int rl   = tid >> 7;           // row within block (0..7)
    const int jj   = tid & 127;          // neighbor index
    const int grow = row0 + rl;          // global row
    const int i    = grow - f * NLOC;    // local atom index (frame-local)

    const float rmin = tab_info[0];
    const float hh   = tab_info[1];
    // DeePMD numpy: hi = 1.0/hh (CR f32 via f64-div+round, double-rounding safe)
    const float hi   = opaque((float)(1.0 / (double)hh));
    const float cut2 = opaque(opaque(1024.0f * hh) + rmin);

    const f32x4 pi = atoms[i];
    const float xi = pi.x, yi = pi.y, zi = pi.z;
    const int itype = __float_as_int(pi.w);

    const int nj = nlist[(size_t)grow * NNEI + jj];
    const int mj = (nj < 0) ? 0 : nj;

    const f32x4 pj = atoms[mj];          // ds_read_b128 gather (LDS)
    const int jtype = __float_as_int(pj.w);

    // ---- strict f32, numpy association, every op barriered (no FMA) ----
    const float dx = opaque(xi - pj.x);
    const float dy = opaque(yi - pj.y);
    const float dz = opaque(zi - pj.z);
    const float x2 = opaque(dx * dx);
    const float y2 = opaque(dy * dy);
    const float z2 = opaque(dz * dz);
    float ss = opaque(opaque(x2 + y2) + z2);
    ss = fmaxf(ss, 1e-30f);

    // CR f32 sqrt, flag-immune: f64 sqrt then round (double-rounding safe)
    const float rr = (float)sqrt((double)ss);

    // uu = (rr - rmin) * hi  (f32 sub, f32 mul — DeePMD numpy recip-multiply)
    const float num = opaque(rr - rmin);
    float uu = opaque(num * hi);
    if (nj == -1) uu = (float)(NSPLINE + 1);

    const int idx = (int)uu;                  // trunc, uu >= 0
    const float fu = opaque(uu - (float)idx);
    int cidx = idx;
    if (cidx < 0) cidx = 0;
    if (cidx > NSPLINE - 1) cidx = NSPLINE - 1;

    // only remaining random VMEM gather: tab coefficients (nontemporal)
    const f32x4* tp = (const f32x4*)tab_data +
        ((size_t)((itype * NTYPES + jtype) * NSPLINE + cidx));
    const f32x4 c4 = __builtin_nontemporal_load(tp);

    float a3 = c4.x, a2 = c4.y, a1 = c4.z, a0 = c4.w;
    if (idx > NSPLINE) { a3 = 0.f; a2 = 0.f; a1 = 0.f; a0 = 0.f; }

    // f32 unfused Horner (DeePMD _calculate_ener)
    float e = opaque(opaque(opaque(opaque(opaque(a3 * fu) + a2) * fu)
                            + a1) * fu) + a0;

    if (rr >= 6.0f || rr >= cut2 || nj == -1) e = 0.0f;

    // ---- reduction: wave shfl (f64) + LDS combine (2 waves per row) ----
    double acc = (double)e;
    #pragma unroll
    for (int off = 32; off; off >>= 1)
        acc += __shfl_xor(acc, off);

    if ((tid & 63) == 0) part[tid >> 6] = acc;
    __syncthreads();
    if (jj == 0)
        out[grow] = (float)(0.5 * (part[rl * 2] + part[rl * 2 + 1]));
}

extern "C" void kernel_launch(void* const* d_in, const int* in_sizes, int n_in,
                              void* d_out, int out_size, void* d_ws, size_t ws_size,
                              hipStream_t stream) {
    const float* coord    = (const float*)d_in[0];
    const int*   atype    = (const int*)  d_in[1];
    const int*   nlist    = (const int*)  d_in[2];
    const float* tab_info = (const float*)d_in[3];
    const float* tab_data = (const float*)d_in[4];
    float* out = (float*)d_out;

    const int blocks = (NF * NLOC) / RPB;        // 768 blocks, 8 rows each
    pairtab_kernel<<<blocks, 1024, 0, stream>>>(coord, atype, nlist, tab_info,
                                                tab_data, out);
}